// Round 8
// baseline (606.985 us; speedup 1.0000x reference)
//
#include <hip/hip_runtime.h>
#include <math.h>

#define N_NODES   50000
#define N_EDGES   1600000
#define N_HEADS   8
#define IN_DIM    512
#define OUT_DIM   64
#define FEAT_DIM  512            // N_HEADS * OUT_DIM
#define LRELU_A   0.2f
#define M_TILES   391            // ceil(50000/128)
#define M_PAD     (M_TILES*128)  // 50048 rows in xh (tail rows read but never stored)

// capacity-slab CSR: node s's edges live at csr_dst[s*CAP .. s*CAP+deg[s]).
// deg ~ Poisson(32); P(any of 50K nodes > 96) ~ 1e-15 (guard-clamped too).
// No count pass, no scan pass -- scatter self-allocates via returning atomic.
#define CAP       96

// fused stage-1 geometry: scatter blocks FIRST (long pole), then convert, prep_b
#define EDGE_BLK   782                      // ceil(1.6M / (256*8))
#define CVT_BLK    25000                    // 6.4M float4 / 256
#define PREPB_BLK  1024                     // 262144 / 256

typedef __attribute__((ext_vector_type(8))) short bf16x8;
typedef __attribute__((ext_vector_type(4))) short bf16x4;
typedef __attribute__((ext_vector_type(4))) float f32x4;

__device__ inline unsigned short f2bf(float f) {
    unsigned int u = __float_as_uint(f);
    u = (u + 0x7FFFu + ((u >> 16) & 1u)) >> 16;   // round-to-nearest-even
    return (unsigned short)u;
}
__device__ inline float bf2f(short s) {
    return __uint_as_float(((unsigned int)(unsigned short)s) << 16);
}

// ---------------------------------------------------------------------------
// Stage 1 (one launch, three barrier-free roles):
//   ids [0, EDGE_BLK)                : scatter  (atomic-latency-bound)
//   ids [EDGE_BLK, EDGE_BLK+CVT_BLK) : convert  (HBM-BW-bound)
//   ids [.., +PREPB_BLK)             : prep_b   (tiny)
// Scatter launches first so its ~136 us spans the dispatch; convert/prep fill
// the machine underneath it (disjoint resources).
// ---------------------------------------------------------------------------
__global__ __launch_bounds__(256) void stage1(const float* __restrict__ x,
                                              unsigned short* __restrict__ xh,
                                              const float* __restrict__ W,
                                              unsigned short* __restrict__ Bt,
                                              const int* __restrict__ src,
                                              const int* __restrict__ dst,
                                              int* __restrict__ deg,
                                              int* __restrict__ csr_dst) {
    const int id = blockIdx.x;
    if (id < EDGE_BLK) {
        // ---- scatter role (unroll 8: 8 independent atomic->store chains) ----
        const int e = (id * 256 + (int)threadIdx.x) * 8;
        if (e < N_EDGES) {
            int4 s0 = *(const int4*)&src[e];
            int4 s1 = *(const int4*)&src[e + 4];
            int4 d0 = *(const int4*)&dst[e];
            int4 d1 = *(const int4*)&dst[e + 4];
            int p0 = atomicAdd(&deg[s0.x], 1);
            int p1 = atomicAdd(&deg[s0.y], 1);
            int p2 = atomicAdd(&deg[s0.z], 1);
            int p3 = atomicAdd(&deg[s0.w], 1);
            int p4 = atomicAdd(&deg[s1.x], 1);
            int p5 = atomicAdd(&deg[s1.y], 1);
            int p6 = atomicAdd(&deg[s1.z], 1);
            int p7 = atomicAdd(&deg[s1.w], 1);
            if (p0 < CAP) csr_dst[(size_t)s0.x * CAP + p0] = d0.x;
            if (p1 < CAP) csr_dst[(size_t)s0.y * CAP + p1] = d0.y;
            if (p2 < CAP) csr_dst[(size_t)s0.z * CAP + p2] = d0.z;
            if (p3 < CAP) csr_dst[(size_t)s0.w * CAP + p3] = d0.w;
            if (p4 < CAP) csr_dst[(size_t)s1.x * CAP + p4] = d1.x;
            if (p5 < CAP) csr_dst[(size_t)s1.y * CAP + p5] = d1.y;
            if (p6 < CAP) csr_dst[(size_t)s1.z * CAP + p6] = d1.z;
            if (p7 < CAP) csr_dst[(size_t)s1.w * CAP + p7] = d1.w;
        }
        return;
    }
    if (id < EDGE_BLK + CVT_BLK) {
        // ---- convert role: x fp32 -> xh bf16 ----
        const int i = (id - EDGE_BLK) * 256 + (int)threadIdx.x;   // float4 index
        if (i >= N_NODES * IN_DIM / 4) return;
        float4 v = ((const float4*)x)[i];
        ushort4 o;
        o.x = f2bf(v.x); o.y = f2bf(v.y); o.z = f2bf(v.z); o.w = f2bf(v.w);
        ((ushort4*)xh)[i] = o;
        return;
    }
    // ---- prep_b role: W [8][512][64] -> Bt [n=512][k=512] ----
    const int t = (id - EDGE_BLK - CVT_BLK) * 256 + (int)threadIdx.x;
    if (t >= FEAT_DIM * IN_DIM) return;
    int n = t >> 9, k = t & 511;
    int h = n >> 6, o = n & 63;
    Bt[t] = f2bf(W[(size_t)h * IN_DIM * OUT_DIM + (size_t)k * OUT_DIM + o]);
}

// ---------------------------------------------------------------------------
// MFMA GEMM (feat = xh @ Bt^T) with fused alpha epilogue.
// Each wave owns one head's full 64-col range (wn = (wid&1)*64, head =
// blockIdx.y*2 + (wid&1)), so alpha_s/d[row,head] = sum over the head's 64
// cols completes exactly in-register: 4 FMA per row + width-16 shfl reduce.
// Computed from fp32 acc (more accurate than the old bf16-feat alpha pass).
// ---------------------------------------------------------------------------
__global__ __launch_bounds__(256) void gemm_alpha(const unsigned short* __restrict__ xh,
                                                  const unsigned short* __restrict__ Bt,
                                                  const float* __restrict__ att_w,
                                                  unsigned short* __restrict__ feat_h,
                                                  float* __restrict__ alpha_s,
                                                  float* __restrict__ alpha_d) {
    __shared__ __align__(16) unsigned short As[128 * 32];  // [m][k], 64 B rows
    __shared__ __align__(16) unsigned short Bs[128 * 32];  // [n][k]
    const int t    = threadIdx.x;
    const int wid  = t >> 6;
    const int lane = t & 63;
    const int m0   = blockIdx.x * 128;
    const int n0   = blockIdx.y * 128;
    const int wm   = (wid >> 1) * 64;
    const int wn   = (wid & 1) * 64;
    const int mr   = lane & 15;
    const int q    = lane >> 4;

    f32x4 acc[4][4];
    #pragma unroll
    for (int i = 0; i < 4; ++i)
        #pragma unroll
        for (int j = 0; j < 4; ++j) acc[i][j] = 0.0f;

    const char* xb = (const char*)xh;
    const char* bb = (const char*)Bt;
    const int o1 = t * 16;         const int row1 = o1 >> 6, kb1 = o1 & 63;
    const int o2 = t * 16 + 4096;  const int row2 = o2 >> 6, kb2 = o2 & 63;
    char* lA1 = ((char*)As) + wid * 1024;
    char* lA2 = ((char*)As) + 4096 + wid * 1024;
    char* lB1 = ((char*)Bs) + wid * 1024;
    char* lB2 = ((char*)Bs) + 4096 + wid * 1024;

    for (int k0 = 0; k0 < IN_DIM; k0 += 32) {
        const int kbyte = k0 * 2;
        __builtin_amdgcn_global_load_lds(
            (const __attribute__((address_space(1))) unsigned int*)(xb + (size_t)(m0 + row1) * (IN_DIM * 2) + kbyte + kb1),
            (__attribute__((address_space(3))) unsigned int*)lA1, 16, 0, 0);
        __builtin_amdgcn_global_load_lds(
            (const __attribute__((address_space(1))) unsigned int*)(xb + (size_t)(m0 + row2) * (IN_DIM * 2) + kbyte + kb2),
            (__attribute__((address_space(3))) unsigned int*)lA2, 16, 0, 0);
        __builtin_amdgcn_global_load_lds(
            (const __attribute__((address_space(1))) unsigned int*)(bb + (size_t)(n0 + row1) * (IN_DIM * 2) + kbyte + kb1),
            (__attribute__((address_space(3))) unsigned int*)lB1, 16, 0, 0);
        __builtin_amdgcn_global_load_lds(
            (const __attribute__((address_space(1))) unsigned int*)(bb + (size_t)(n0 + row2) * (IN_DIM * 2) + kbyte + kb2),
            (__attribute__((address_space(3))) unsigned int*)lB2, 16, 0, 0);
        __syncthreads();

        bf16x8 a[4], b[4];
        #pragma unroll
        for (int i = 0; i < 4; ++i)
            a[i] = *(const bf16x8*)&As[(wm + i * 16 + mr) * 32 + q * 8];
        #pragma unroll
        for (int j = 0; j < 4; ++j)
            b[j] = *(const bf16x8*)&Bs[(wn + j * 16 + mr) * 32 + q * 8];
        #pragma unroll
        for (int i = 0; i < 4; ++i)
            #pragma unroll
            for (int j = 0; j < 4; ++j)
                acc[i][j] = __builtin_amdgcn_mfma_f32_16x16x32_bf16(a[i], b[j], acc[i][j], 0, 0, 0);
        __syncthreads();
    }

    // ---- feat store ----
    #pragma unroll
    for (int i = 0; i < 4; ++i) {
        #pragma unroll
        for (int j = 0; j < 4; ++j) {
            int col = n0 + wn + j * 16 + mr;
            #pragma unroll
            for (int r = 0; r < 4; ++r) {
                int row = m0 + wm + i * 16 + q * 4 + r;
                if (row < N_NODES)
                    feat_h[(size_t)row * FEAT_DIM + col] = f2bf(acc[i][j][r]);
            }
        }
    }

    // ---- fused alpha epilogue ----
    const int h = blockIdx.y * 2 + (wid & 1);   // this wave's head
    float a1[4], a2[4];
    #pragma unroll
    for (int j = 0; j < 4; ++j) {
        a1[j] = att_w[h * 128 + j * 16 + mr];
        a2[j] = att_w[h * 128 + 64 + j * 16 + mr];
    }
    #pragma unroll
    for (int i = 0; i < 4; ++i) {
        #pragma unroll
        for (int r = 0; r < 4; ++r) {
            float s = 0.f, d = 0.f;
            #pragma unroll
            for (int j = 0; j < 4; ++j) {
                float v = acc[i][j][r];
                s += v * a1[j];
                d += v * a2[j];
            }
            #pragma unroll
            for (int off = 1; off < 16; off <<= 1) {
                s += __shfl_xor(s, off);
                d += __shfl_xor(d, off);
            }
            int row = m0 + wm + i * 16 + q * 4 + r;
            if (mr == 0 && row < N_NODES) {
                alpha_s[row * N_HEADS + h] = s;
                alpha_d[row * N_HEADS + h] = d;
            }
        }
    }
}

// ---------------------------------------------------------------------------
// Fused attention+aggregation, column-split into 2 sequential passes
// (hg=0: heads 0-3, hg=1: heads 4-7; 512 B/edge gather from a 25.6 MB
// half-table). 2 waves/node (edge-range split, LDS pair-reduce),
// flat unroll-16 stream. CSR is the capacity slab: start=node*CAP, deg[].
// ---------------------------------------------------------------------------
__global__ __launch_bounds__(256) void agg_kernel(const unsigned short* __restrict__ feat_h,
                                                  const float* __restrict__ alpha_s,
                                                  const float* __restrict__ alpha_d,
                                                  const int* __restrict__ deg,
                                                  const int* __restrict__ csr_dst,
                                                  float* __restrict__ out,
                                                  int hg) {
    __shared__ float red[2][64][5];
    const int wv   = __builtin_amdgcn_readfirstlane(threadIdx.x >> 6);  // uniform
    const int lane = threadIdx.x & 63;
    const int node = blockIdx.x * 2 + (wv >> 1);   // uniform (N_NODES even)
    const int half = wv & 1;                       // uniform
    const int h    = hg * 4 + (lane >> 4);

    const int dg    = deg[node];
    const int start = node * CAP;
    const int lo    = start + ((dg * half) >> 1);
    const int hi    = start + ((dg * (half + 1)) >> 1);
    const int cnt2  = hi - lo;
    const float as  = alpha_s[node * N_HEADS + h];
    const int* cd   = csr_dst + lo;                // uniform pointer -> s_load
    const unsigned short* fb = feat_h + hg * 256 + lane * 4;

    float sacc = 0.f;
    float acc[4] = {};

    int j = 0;
    for (; j + 16 <= cnt2; j += 16) {
        int d[16];
        #pragma unroll
        for (int k = 0; k < 16; ++k) d[k] = cd[j + k];
        float ad[16];
        #pragma unroll
        for (int k = 0; k < 16; ++k) ad[k] = alpha_d[(size_t)d[k] * N_HEADS + h];
        bf16x4 f[16];
        #pragma unroll
        for (int k = 0; k < 16; ++k)
            f[k] = *(const bf16x4*)&fb[(size_t)d[k] * FEAT_DIM];
        float e[16];
        #pragma unroll
        for (int k = 0; k < 16; ++k) {
            float z = as + ad[k];
            z = z > 0.f ? z : LRELU_A * z;
            e[k] = __expf(z);
        }
        float s0 = 0.f;
        #pragma unroll
        for (int k = 0; k < 16; ++k) s0 += e[k];
        sacc += s0;
        #pragma unroll
        for (int i = 0; i < 4; ++i) {
            float a = acc[i];
            #pragma unroll
            for (int k = 0; k < 16; ++k) a += e[k] * bf2f(f[k][i]);
            acc[i] = a;
        }
    }
    for (; j + 4 <= cnt2; j += 4) {
        int d[4];
        #pragma unroll
        for (int k = 0; k < 4; ++k) d[k] = cd[j + k];
        float ad[4];
        #pragma unroll
        for (int k = 0; k < 4; ++k) ad[k] = alpha_d[(size_t)d[k] * N_HEADS + h];
        bf16x4 f[4];
        #pragma unroll
        for (int k = 0; k < 4; ++k)
            f[k] = *(const bf16x4*)&fb[(size_t)d[k] * FEAT_DIM];
        float e[4];
        #pragma unroll
        for (int k = 0; k < 4; ++k) {
            float z = as + ad[k];
            z = z > 0.f ? z : LRELU_A * z;
            e[k] = __expf(z);
        }
        sacc += (e[0] + e[1]) + (e[2] + e[3]);
        #pragma unroll
        for (int i = 0; i < 4; ++i) {
            float a = acc[i];
            #pragma unroll
            for (int k = 0; k < 4; ++k) a += e[k] * bf2f(f[k][i]);
            acc[i] = a;
        }
    }
    for (; j < cnt2; ++j) {
        int dd = cd[j];
        float ad0 = alpha_d[(size_t)dd * N_HEADS + h];
        bf16x4 f0 = *(const bf16x4*)&fb[(size_t)dd * FEAT_DIM];
        float z = as + ad0; z = z > 0.f ? z : LRELU_A * z;
        float e0 = __expf(z);
        sacc += e0;
        #pragma unroll
        for (int i = 0; i < 4; ++i) acc[i] += e0 * bf2f(f0[i]);
    }

    const int pr = wv >> 1;
    if (half == 1) {
        #pragma unroll
        for (int i = 0; i < 4; ++i) red[pr][lane][i] = acc[i];
        red[pr][lane][4] = sacc;
    }
    __syncthreads();
    if (half == 0) {
        #pragma unroll
        for (int i = 0; i < 4; ++i) acc[i] += red[pr][lane][i];
        sacc += red[pr][lane][4];
        const float inv = (dg > 0) ? 1.f / sacc : 0.f;
        f32x4 o0 = { fmaxf(acc[0] * inv, 0.f), fmaxf(acc[1] * inv, 0.f),
                     fmaxf(acc[2] * inv, 0.f), fmaxf(acc[3] * inv, 0.f) };
        f32x4* op = (f32x4*)(out + (size_t)node * FEAT_DIM + hg * 256 + lane * 4);
        __builtin_nontemporal_store(o0, op);
    }
}

// ---------------------------------------------------------------------------
extern "C" void kernel_launch(void* const* d_in, const int* in_sizes, int n_in,
                              void* d_out, int out_size, void* d_ws, size_t ws_size,
                              hipStream_t stream) {
    const float* x     = (const float*)d_in[0];
    const float* W     = (const float*)d_in[1];
    const float* att_w = (const float*)d_in[2];
    const int*   src   = (const int*)d_in[3];
    const int*   dst   = (const int*)d_in[4];
    float* out = (float*)d_out;

    char* ws = (char*)d_ws;
    size_t off = 0;
    auto alloc = [&](size_t bytes) {
        void* p = ws + off;
        off += (bytes + 255) & ~(size_t)255;
        return p;
    };
    unsigned short* feat_h = (unsigned short*)alloc((size_t)N_NODES * FEAT_DIM * sizeof(short)); // 51.2 MB
    unsigned short* xh     = (unsigned short*)alloc((size_t)M_PAD * IN_DIM * sizeof(short));     // 51.2 MB
    unsigned short* Bt     = (unsigned short*)alloc((size_t)FEAT_DIM * IN_DIM * sizeof(short));  // 0.5 MB
    float* alpha_s = (float*)alloc((size_t)N_NODES * N_HEADS * sizeof(float));                   // 1.6 MB
    float* alpha_d = (float*)alloc((size_t)N_NODES * N_HEADS * sizeof(float));                   // 1.6 MB
    int*   deg     = (int*)alloc((size_t)N_NODES * sizeof(int));                                 // 0.2 MB
    int*   csr_dst = (int*)alloc((size_t)N_NODES * CAP * sizeof(int));                           // 19.2 MB

    (void)hipMemsetAsync(deg, 0, (size_t)N_NODES * sizeof(int), stream);

    // Launch 1: scatter (atomic-bound, FIRST) || convert (BW) || prep_b (tiny)
    stage1<<<EDGE_BLK + CVT_BLK + PREPB_BLK, 256, 0, stream>>>(
        x, xh, W, Bt, src, dst, deg, csr_dst);

    // Launch 2: GEMM + fused alpha epilogue
    dim3 ggrid(M_TILES, FEAT_DIM / 128);
    gemm_alpha<<<ggrid, 256, 0, stream>>>(xh, Bt, att_w, feat_h, alpha_s, alpha_d);

    // Launches 3-4: aggregation, column-split
    agg_kernel<<<N_NODES / 2, 256, 0, stream>>>(feat_h, alpha_s, alpha_d, deg, csr_dst, out, 0);
    agg_kernel<<<N_NODES / 2, 256, 0, stream>>>(feat_h, alpha_s, alpha_d, deg, csr_dst, out, 1);
}